// Round 15
// baseline (35.302 us; speedup 1.0000x reference)
//
#include <hip/hip_runtime.h>
#include <cstdint>
#include <cstddef>

typedef __attribute__((ext_vector_type(8))) short bf16x8;
typedef __attribute__((ext_vector_type(8))) _Float16 f16x8;
typedef __attribute__((ext_vector_type(4))) float f32x4;
typedef __attribute__((ext_vector_type(2))) float f32x2;
typedef __attribute__((ext_vector_type(2))) unsigned int u32x2;

static constexpr int BROWS = 262144;
static constexpr int DIM   = 64;
static constexpr int NC    = 256;
static constexpr int OUTD  = 18;
static constexpr int BM    = 32;     // rows per chunk
static constexpr int NBLK  = 1024;
static constexpr int NCH   = BROWS / BM / NBLK;  // 8

__device__ __forceinline__ unsigned cvt_pk_bf16(float a, float b) {
  unsigned r;
  asm("v_cvt_pk_bf16_f32 %0, %1, %2" : "=v"(r) : "v"(a), "v"(b));
  return r;
}

union U4 { unsigned u[4]; bf16x8 v; };

// pack 8 f32 -> 8 bf16 (RN), order-preserving
__device__ __forceinline__ bf16x8 pack8(const float* s) {
  U4 r;
#pragma unroll
  for (int p = 0; p < 4; ++p) r.u[p] = cvt_pk_bf16(s[2*p], s[2*p+1]);
  return r.v;
}

// NOTE (gfx950): __launch_bounds__(512, 8) forces a 32-VGPR cap -> scratch
// spill (R9). (512,4) observed safe (R10-R14: VGPR 44-64, no spill).
__global__ __launch_bounds__(512, 4) void rbf_fused(
    const float* __restrict__ x,  const float* __restrict__ Wr,
    const float* __restrict__ br, const float* __restrict__ Wl,
    const float* __restrict__ bl, float* __restrict__ out)
{
  // 33 KB total -> 4 blocks/CU (32 waves/CU, HW max). feat single-buffered
  // (2 barriers/chunk); xh16 stays double-buffered for the x pipeline.
  __shared__ __align__(16) unsigned short xh16[2][BM * DIM];    // x as fp16 bits, 2 x 4 KB
  __shared__ __align__(16) unsigned short feat[BM * NC];        // feat bf16 bits, 16 KB
  __shared__ __align__(16) unsigned short wlds[OUTD * NC];      // W_lin bf16, 9 KB

  const int tid  = threadIdx.x;
  const int wav  = tid >> 6;      // 0..7
  const int lane = tid & 63;
  const int li   = lane & 15;
  const int g    = lane >> 4;

  const float S1 = 0.22507907903927651f;  // sqrt(2)/(2*pi): proj in revolutions
  const float SC = 0.08838834764831845f;  // sqrt(2/256), applied to feat

  // ---- stage W_lin -> LDS (bf16, swizzled). Verbatim R14. ----
  for (int idx = tid; idx < OUTD * 32; idx += 512) {
    const int r = idx >> 5, c = idx & 31;
    f32x4 v0 = *(const f32x4*)(Wl + r*NC + 8*c);
    f32x4 v1 = *(const f32x4*)(Wl + r*NC + 8*c + 4);
    float v[8];
    v[0]=v0.x; v[1]=v0.y; v[2]=v0.z; v[3]=v0.w;
    v[4]=v1.x; v[5]=v1.y; v[6]=v1.z; v[7]=v1.w;
    *(bf16x8*)(&wlds[r*NC + 8*(c ^ (r & 7))]) = pack8(v);
  }

  // ---- hoist A1 = (S1 * W_rbf)^T tile fragments, single fp16.  nt = 2*wav + q ----
  f16x8 a1[2][2];
#pragma unroll
  for (int q = 0; q < 2; ++q) {
    const int n = 16 * (2*wav + q) + li;      // component index
#pragma unroll
    for (int kb = 0; kb < 2; ++kb) {
      f16x8 f;
#pragma unroll
      for (int j = 0; j < 8; ++j)
        f[j] = (_Float16)(Wr[(size_t)(32*kb + 8*g + j) * NC + n] * S1);
      a1[q][kb] = f;
    }
  }
  f32x4 brf[2];
#pragma unroll
  for (int q = 0; q < 2; ++q)
    brf[q] = *(const f32x4*)(br + 16*(2*wav + q) + 4*g);

  const f32x4 bl0 = *(const f32x4*)(bl + 4*g);   // o = 4g..4g+3 <= 15 < 18
  const float bl16 = bl[16], bl17 = bl[17];
  const int rowc = (li < 2) ? (16 + li) : li;    // o-tile-1 A2 row (dummy rows harmless)

  const int sr = tid >> 4;   // staging row 0..31
  const int g4 = tid & 15;   // staging 4-float granule 0..15
  const int cbase = blockIdx.x * NCH;

  // stage-write: f32x4 -> fp16 (RNE), 8B write, 16B-chunk XOR swizzle
  // (chunk c16 = (g4>>1)^(sr&7)).
  auto stage_write = [&](int p, f32x4 v) {
    union { _Float16 h[4]; u32x2 u; } cv;
    cv.h[0] = (_Float16)v.x; cv.h[1] = (_Float16)v.y;
    cv.h[2] = (_Float16)v.z; cv.h[3] = (_Float16)v.w;
    const int offs = sr*DIM + 8*((g4 >> 1) ^ (sr & 7)) + 4*(g4 & 1);
    *(u32x2*)(&xh16[p][offs]) = cv.u;
  };

  // prologue: stage chunk 0 into buf 0 (also covers wlds/a1 init sync)
  {
    const float* xp = x + ((size_t)cbase * BM + sr) * DIM + 4*g4;
    stage_write(0, *(const f32x4*)xp);
  }
  asm volatile("s_waitcnt lgkmcnt(0)" ::: "memory");
  __builtin_amdgcn_s_barrier();
  asm volatile("" ::: "memory");

  for (int i = 0; i < NCH; ++i) {
    const int pb = i & 1;
    const int R  = (cbase + i) * BM;

    // ---- S1a: issue next chunk's x loads early (latency hides under P1) ----
    f32x4 pnext;
    const bool havenext = (i + 1 < NCH);
    if (havenext) {
      const float* xp = x + ((size_t)(R + BM) + sr) * DIM + 4*g4;
      pnext = *(const f32x4*)xp;
    }

    // ---- S1b: P1 on xh16[pb] -> feat. Single fp16 pass. Verbatim R14. ----
#pragma unroll
    for (int rt = 0; rt < 2; ++rt) {
      const int rr = rt*16 + li;
      const int m  = li & 7;                   // == rr&7
      f16x8 bh[2];
#pragma unroll
      for (int kb = 0; kb < 2; ++kb) {
        const int slot = 8*((4*kb + g) ^ m);
        bh[kb] = *(const f16x8*)(&xh16[pb][rr*DIM + slot]);
      }
      f32x4 acc[2];
#pragma unroll
      for (int q = 0; q < 2; ++q) acc[q] = f32x4{0.f, 0.f, 0.f, 0.f};
#pragma unroll
      for (int kb = 0; kb < 2; ++kb) {
#pragma unroll
        for (int q = 0; q < 2; ++q)
          acc[q] = __builtin_amdgcn_mfma_f32_16x16x32_f16(a1[q][kb], bh[kb], acc[q], 0, 0, 0);
      }
      // rev = proj + b_rbf; feat = cos(2*pi*rev)*SC, bf16, packed 8B write.
#pragma unroll
      for (int q = 0; q < 2; ++q) {
        float c4[4];
#pragma unroll
        for (int j = 0; j < 4; ++j) {
          float rev = acc[q][j] + brf[q][j];
          float f   = rev - floorf(rev);                 // [0,1) revolutions
          c4[j] = __builtin_amdgcn_cosf(f) * SC;
        }
        u32x2 pk;
        pk.x = cvt_pk_bf16(c4[0], c4[1]);
        pk.y = cvt_pk_bf16(c4[2], c4[3]);
        const int nt   = 2*wav + q;
        const int slot = (2*nt + (g >> 1)) ^ m;          // 16B-chunk XOR swizzle
        *(u32x2*)(&feat[rr*256 + slot*8 + (g & 1)*4]) = pk;
      }
    }

    // ---- S1c: write next chunk's xh16 (other parity) ----
    if (havenext) stage_write(pb ^ 1, pnext);

    // ---- B1: feat ready, xh16[pb^1] staged ----
    asm volatile("s_waitcnt lgkmcnt(0)" ::: "memory");
    __builtin_amdgcn_s_barrier();
    asm volatile("" ::: "memory");

    // ---- S2: P2 on feat, spread over 4 waves: wave = (ot, rt2). Verbatim R14. ----
    if (wav < 4) {
      const int rt2 = wav & 1;
      const int ot  = wav >> 1;
      const int rr  = rt2*16 + li;              // rows 0..31
      const int m   = li & 7;                   // == rr&7
      const int arow = (ot == 0) ? li : rowc;
      const int asw  = arow & 7;
      f32x4 acc2 = f32x4{0.f,0.f,0.f,0.f};
#pragma unroll
      for (int kb = 0; kb < 8; ++kb) {
        bf16x8 b2  = *(const bf16x8*)(&feat[rr*256 + (((4*kb + g) ^ m) * 8)]);
        bf16x8 a2f = *(const bf16x8*)(&wlds[arow*NC + 8*((4*kb + g) ^ asw)]);
        acc2 = __builtin_amdgcn_mfma_f32_16x16x32_bf16(a2f, b2, acc2, 0, 0, 0);
      }
      float* op = out + (size_t)(R + rr) * OUTD;
      if (ot == 0) {
        f32x2 s0; s0.x = acc2.x + bl0.x; s0.y = acc2.y + bl0.y;
        f32x2 s1; s1.x = acc2.z + bl0.z; s1.y = acc2.w + bl0.w;
        *(f32x2*)(op + 4*g)     = s0;   // o = 4g..4g+3 (all < 16)
        *(f32x2*)(op + 4*g + 2) = s1;
      } else if (g == 0) {              // o = 16,17
        f32x2 s2; s2.x = acc2.x + bl16; s2.y = acc2.y + bl17;
        *(f32x2*)(op + 16) = s2;
      }
    }

    // ---- B2: feat consumed; next P1 may rewrite it ----
    asm volatile("s_waitcnt lgkmcnt(0)" ::: "memory");
    __builtin_amdgcn_s_barrier();
    asm volatile("" ::: "memory");
  }
}

extern "C" void kernel_launch(void* const* d_in, const int* in_sizes, int n_in,
                              void* d_out, int out_size, void* d_ws, size_t ws_size,
                              hipStream_t stream) {
  (void)in_sizes; (void)n_in; (void)d_ws; (void)ws_size; (void)out_size;
  const float* x  = (const float*)d_in[0];
  const float* Wr = (const float*)d_in[1];
  const float* br = (const float*)d_in[2];
  const float* Wl = (const float*)d_in[3];
  const float* bl = (const float*)d_in[4];
  rbf_fused<<<NBLK, 512, 0, stream>>>(x, Wr, br, Wl, bl, (float*)d_out);
}

// Round 18
// 34.076 us; speedup vs baseline: 1.0360x; 1.0360x over previous
//
#include <hip/hip_runtime.h>
#include <cstdint>
#include <cstddef>

typedef __attribute__((ext_vector_type(8))) short bf16x8;
typedef __attribute__((ext_vector_type(8))) _Float16 f16x8;
typedef __attribute__((ext_vector_type(4))) float f32x4;
typedef __attribute__((ext_vector_type(2))) float f32x2;
typedef __attribute__((ext_vector_type(2))) unsigned int u32x2;

static constexpr int BROWS = 262144;
static constexpr int DIM   = 64;
static constexpr int NC    = 256;
static constexpr int OUTD  = 18;
static constexpr int BM    = 32;     // rows per chunk
static constexpr int NBLK  = 1024;
static constexpr int NCH   = BROWS / BM / NBLK;  // 8

__device__ __forceinline__ unsigned cvt_pk_bf16(float a, float b) {
  unsigned r;
  asm("v_cvt_pk_bf16_f32 %0, %1, %2" : "=v"(r) : "v"(a), "v"(b));
  return r;
}

union U4 { unsigned u[4]; bf16x8 v; };

// pack 8 f32 -> 8 bf16 (RN), order-preserving
__device__ __forceinline__ bf16x8 pack8(const float* s) {
  U4 r;
#pragma unroll
  for (int p = 0; p < 4; ++p) r.u[p] = cvt_pk_bf16(s[2*p], s[2*p+1]);
  return r.v;
}

// NOTE (gfx950): __launch_bounds__(512, 8) forces a 32-VGPR cap -> scratch
// spill (R9). (512,4) observed safe (R10-R15: VGPR 44-64, no spill).
// NOTE: the epilogue-rewrite family {C-init=brf, SC-fold into wlds, v_fract
// asm, cvt_pkrtz} produced 0.15-0.2-class failures in three independent
// skeletons (R5/R7/R17) with no identifiable mechanism — BANNED. This file
// keeps R14's plain epilogue verbatim.
__global__ __launch_bounds__(512, 4) void rbf_fused(
    const float* __restrict__ x,  const float* __restrict__ Wr,
    const float* __restrict__ br, const float* __restrict__ Wl,
    const float* __restrict__ bl, float* __restrict__ out)
{
  // R14 skeleton (best: 33.1us): xh16 + featb double-buffered, ONE barrier
  // per chunk (R15's 2-barrier variant was 2.2us worse).
  __shared__ __align__(16) unsigned short xh16[2][BM * DIM];    // x as fp16 bits, 2 x 4 KB
  __shared__ __align__(16) unsigned short featb[2][BM * NC];    // feat bf16 bits, 2 x 16 KB
  __shared__ __align__(16) unsigned short wlds[OUTD * NC];      // W_lin bf16 (raw), 9 KB

  const int tid  = threadIdx.x;
  const int wav  = tid >> 6;      // 0..7
  const int lane = tid & 63;
  const int li   = lane & 15;
  const int g    = lane >> 4;

  const float S1 = 0.22507907903927651f;  // sqrt(2)/(2*pi): proj in revolutions
  const float SC = 0.08838834764831845f;  // sqrt(2/256), applied to feat (R14 semantics)

  // ---- stage W_lin -> LDS (bf16, swizzled). Verbatim R14. ----
  for (int idx = tid; idx < OUTD * 32; idx += 512) {
    const int r = idx >> 5, c = idx & 31;
    f32x4 v0 = *(const f32x4*)(Wl + r*NC + 8*c);
    f32x4 v1 = *(const f32x4*)(Wl + r*NC + 8*c + 4);
    float v[8];
    v[0]=v0.x; v[1]=v0.y; v[2]=v0.z; v[3]=v0.w;
    v[4]=v1.x; v[5]=v1.y; v[6]=v1.z; v[7]=v1.w;
    *(bf16x8*)(&wlds[r*NC + 8*(c ^ (r & 7))]) = pack8(v);
  }

  // ---- hoist A1 = (S1 * W_rbf)^T tile fragments, single fp16.  nt = 2*wav + q ----
  f16x8 a1[2][2];
#pragma unroll
  for (int q = 0; q < 2; ++q) {
    const int n = 16 * (2*wav + q) + li;      // component index
#pragma unroll
    for (int kb = 0; kb < 2; ++kb) {
      f16x8 f;
#pragma unroll
      for (int j = 0; j < 8; ++j)
        f[j] = (_Float16)(Wr[(size_t)(32*kb + 8*g + j) * NC + n] * S1);
      a1[q][kb] = f;
    }
  }
  f32x4 brf[2];
#pragma unroll
  for (int q = 0; q < 2; ++q)
    brf[q] = *(const f32x4*)(br + 16*(2*wav + q) + 4*g);

  const f32x4 bl0 = *(const f32x4*)(bl + 4*g);   // o = 4g..4g+3 <= 15 < 18
  const float bl16 = bl[16], bl17 = bl[17];
  const int rowc = (li < 2) ? (16 + li) : li;    // o-tile-1 A2 row (dummy rows harmless)

  const int sr = tid >> 4;   // staging row 0..31
  const int g4 = tid & 15;   // staging 4-float granule 0..15
  const int cbase = blockIdx.x * NCH;

  // stage-write: f32x4 -> fp16 (RNE), 8B write, 16B-chunk XOR swizzle
  // (chunk c16 = (g4>>1)^(sr&7)). Verbatim R14.
  auto stage_write = [&](int p, f32x4 v) {
    union { _Float16 h[4]; u32x2 u; } cv;
    cv.h[0] = (_Float16)v.x; cv.h[1] = (_Float16)v.y;
    cv.h[2] = (_Float16)v.z; cv.h[3] = (_Float16)v.w;
    const int offs = sr*DIM + 8*((g4 >> 1) ^ (sr & 7)) + 4*(g4 & 1);
    *(u32x2*)(&xh16[p][offs]) = cv.u;
  };

  // prologue: stage chunk 0 into buf 0 (also covers wlds/a1 init sync)
  {
    const float* xp = x + ((size_t)cbase * BM + sr) * DIM + 4*g4;
    stage_write(0, *(const f32x4*)xp);
  }
  asm volatile("s_waitcnt lgkmcnt(0)" ::: "memory");
  __builtin_amdgcn_s_barrier();
  asm volatile("" ::: "memory");

  for (int i = 0; i < NCH; ++i) {
    const int pb = i & 1;
    const int R  = (cbase + i) * BM;

    // ---- S1a: issue next chunk's x loads early (latency hides under P1) ----
    f32x4 pnext;
    const bool havenext = (i + 1 < NCH);
    if (havenext) {
      const float* xp = x + ((size_t)(R + BM) + sr) * DIM + 4*g4;
      pnext = *(const f32x4*)xp;
    }

    // ---- S1b: P1 on xh16[pb] -> featb[pb]. Single fp16 pass. Verbatim R14. ----
#pragma unroll
    for (int rt = 0; rt < 2; ++rt) {
      const int rr = rt*16 + li;
      const int m  = li & 7;                   // == rr&7
      f16x8 bh[2];
#pragma unroll
      for (int kb = 0; kb < 2; ++kb) {
        const int slot = 8*((4*kb + g) ^ m);
        bh[kb] = *(const f16x8*)(&xh16[pb][rr*DIM + slot]);
      }
      f32x4 acc[2];
#pragma unroll
      for (int q = 0; q < 2; ++q) acc[q] = f32x4{0.f, 0.f, 0.f, 0.f};
#pragma unroll
      for (int kb = 0; kb < 2; ++kb) {
#pragma unroll
        for (int q = 0; q < 2; ++q)
          acc[q] = __builtin_amdgcn_mfma_f32_16x16x32_f16(a1[q][kb], bh[kb], acc[q], 0, 0, 0);
      }
      // rev = proj + b_rbf; feat = cos(2*pi*rev)*SC, bf16, packed 8B write.
#pragma unroll
      for (int q = 0; q < 2; ++q) {
        float c4[4];
#pragma unroll
        for (int j = 0; j < 4; ++j) {
          float rev = acc[q][j] + brf[q][j];
          float f   = rev - floorf(rev);                 // [0,1) revolutions
          c4[j] = __builtin_amdgcn_cosf(f) * SC;
        }
        u32x2 pk;
        pk.x = cvt_pk_bf16(c4[0], c4[1]);
        pk.y = cvt_pk_bf16(c4[2], c4[3]);
        const int nt   = 2*wav + q;
        const int slot = (2*nt + (g >> 1)) ^ m;          // 16B-chunk XOR swizzle
        *(u32x2*)(&featb[pb][rr*256 + slot*8 + (g & 1)*4]) = pk;
      }
    }

    // ---- S1c: write next chunk's xh16 (other parity) ----
    if (havenext) stage_write(pb ^ 1, pnext);

    // ---- single barrier per chunk ----
    asm volatile("s_waitcnt lgkmcnt(0)" ::: "memory");
    __builtin_amdgcn_s_barrier();
    asm volatile("" ::: "memory");

    // ---- S2: P2 on featb[pb]. Alternate the P2 wave-group per chunk to
    // balance cumulative work (R14 pinned it to waves 0-3, making them the
    // critical path): even chunks -> waves 0-3, odd chunks -> waves 4-7.
    // Same mapping/stores via pw; barrier is outside the gate. ----
    {
      const int pw = wav - ((i & 1) << 2);     // 0..3 for the active group
      if (pw >= 0 && pw < 4) {
        const int rt2 = pw & 1;
        const int ot  = pw >> 1;
        const int rr  = rt2*16 + li;           // rows 0..31
        const int m   = li & 7;                // == rr&7
        const int arow = (ot == 0) ? li : rowc;
        const int asw  = arow & 7;
        f32x4 acc2 = f32x4{0.f,0.f,0.f,0.f};
#pragma unroll
        for (int kb = 0; kb < 8; ++kb) {
          bf16x8 b2  = *(const bf16x8*)(&featb[pb][rr*256 + (((4*kb + g) ^ m) * 8)]);
          bf16x8 a2f = *(const bf16x8*)(&wlds[arow*NC + 8*((4*kb + g) ^ asw)]);
          acc2 = __builtin_amdgcn_mfma_f32_16x16x32_bf16(a2f, b2, acc2, 0, 0, 0);
        }
        float* op = out + (size_t)(R + rr) * OUTD;
        if (ot == 0) {
          f32x2 s0; s0.x = acc2.x + bl0.x; s0.y = acc2.y + bl0.y;
          f32x2 s1; s1.x = acc2.z + bl0.z; s1.y = acc2.w + bl0.w;
          *(f32x2*)(op + 4*g)     = s0;   // o = 4g..4g+3 (all < 16)
          *(f32x2*)(op + 4*g + 2) = s1;
        } else if (g == 0) {              // o = 16,17
          f32x2 s2; s2.x = acc2.x + bl16; s2.y = acc2.y + bl17;
          *(f32x2*)(op + 16) = s2;
        }
      }
    }
  }
}

extern "C" void kernel_launch(void* const* d_in, const int* in_sizes, int n_in,
                              void* d_out, int out_size, void* d_ws, size_t ws_size,
                              hipStream_t stream) {
  (void)in_sizes; (void)n_in; (void)d_ws; (void)ws_size; (void)out_size;
  const float* x  = (const float*)d_in[0];
  const float* Wr = (const float*)d_in[1];
  const float* br = (const float*)d_in[2];
  const float* Wl = (const float*)d_in[3];
  const float* bl = (const float*)d_in[4];
  rbf_fused<<<NBLK, 512, 0, stream>>>(x, Wr, br, Wl, bl, (float*)d_out);
}

// Round 19
// 31.907 us; speedup vs baseline: 1.1064x; 1.0680x over previous
//
#include <hip/hip_runtime.h>
#include <cstdint>
#include <cstddef>

typedef __attribute__((ext_vector_type(8))) short bf16x8;
typedef __attribute__((ext_vector_type(8))) _Float16 f16x8;
typedef __attribute__((ext_vector_type(4))) float f32x4;
typedef __attribute__((ext_vector_type(2))) float f32x2;
typedef __attribute__((ext_vector_type(2))) unsigned int u32x2;

static constexpr int BROWS = 262144;
static constexpr int DIM   = 64;
static constexpr int NC    = 256;
static constexpr int OUTD  = 18;
static constexpr int BM    = 32;     // rows per chunk
static constexpr int NBLK  = 512;    // exactly 2 blocks/CU x 256 CUs -> zero drain
static constexpr int NCH   = BROWS / BM / NBLK;  // 16

__device__ __forceinline__ unsigned cvt_pk_bf16(float a, float b) {
  unsigned r;
  asm("v_cvt_pk_bf16_f32 %0, %1, %2" : "=v"(r) : "v"(a), "v"(b));
  return r;
}

union U4 { unsigned u[4]; bf16x8 v; };

// pack 8 f32 -> 8 bf16 (RN), order-preserving
__device__ __forceinline__ bf16x8 pack8(const float* s) {
  U4 r;
#pragma unroll
  for (int p = 0; p < 4; ++p) r.u[p] = cvt_pk_bf16(s[2*p], s[2*p+1]);
  return r.v;
}

// NOTE (gfx950): __launch_bounds__(512, 8) forces a 32-VGPR cap -> scratch
// spill (R9). (512,4) observed safe (R10-R18: VGPR 44-64, no spill).
// NOTE: the epilogue-rewrite family {C-init=brf, SC-fold into wlds, v_fract
// asm, cvt_pkrtz} produced 0.15-0.2-class failures in three independent
// skeletons (R5/R7/R17) with no identifiable mechanism — BANNED. This file
// keeps R14's plain epilogue verbatim.
__global__ __launch_bounds__(512, 4) void rbf_fused(
    const float* __restrict__ x,  const float* __restrict__ Wr,
    const float* __restrict__ br, const float* __restrict__ Wl,
    const float* __restrict__ bl, float* __restrict__ out)
{
  // R14 skeleton (best: 33.1us): xh16 + featb double-buffered, ONE barrier
  // per chunk (R15's 2-barrier variant was 2.2us worse).
  __shared__ __align__(16) unsigned short xh16[2][BM * DIM];    // x as fp16 bits, 2 x 4 KB
  __shared__ __align__(16) unsigned short featb[2][BM * NC];    // feat bf16 bits, 2 x 16 KB
  __shared__ __align__(16) unsigned short wlds[OUTD * NC];      // W_lin bf16 (raw), 9 KB

  const int tid  = threadIdx.x;
  const int wav  = tid >> 6;      // 0..7
  const int lane = tid & 63;
  const int li   = lane & 15;
  const int g    = lane >> 4;

  const float S1 = 0.22507907903927651f;  // sqrt(2)/(2*pi): proj in revolutions
  const float SC = 0.08838834764831845f;  // sqrt(2/256), applied to feat (R14 semantics)

  // ---- stage W_lin -> LDS (bf16, swizzled). Verbatim R14. ----
  for (int idx = tid; idx < OUTD * 32; idx += 512) {
    const int r = idx >> 5, c = idx & 31;
    f32x4 v0 = *(const f32x4*)(Wl + r*NC + 8*c);
    f32x4 v1 = *(const f32x4*)(Wl + r*NC + 8*c + 4);
    float v[8];
    v[0]=v0.x; v[1]=v0.y; v[2]=v0.z; v[3]=v0.w;
    v[4]=v1.x; v[5]=v1.y; v[6]=v1.z; v[7]=v1.w;
    *(bf16x8*)(&wlds[r*NC + 8*(c ^ (r & 7))]) = pack8(v);
  }

  // ---- hoist A1 = (S1 * W_rbf)^T tile fragments, single fp16.  nt = 2*wav + q ----
  f16x8 a1[2][2];
#pragma unroll
  for (int q = 0; q < 2; ++q) {
    const int n = 16 * (2*wav + q) + li;      // component index
#pragma unroll
    for (int kb = 0; kb < 2; ++kb) {
      f16x8 f;
#pragma unroll
      for (int j = 0; j < 8; ++j)
        f[j] = (_Float16)(Wr[(size_t)(32*kb + 8*g + j) * NC + n] * S1);
      a1[q][kb] = f;
    }
  }
  f32x4 brf[2];
#pragma unroll
  for (int q = 0; q < 2; ++q)
    brf[q] = *(const f32x4*)(br + 16*(2*wav + q) + 4*g);

  const f32x4 bl0 = *(const f32x4*)(bl + 4*g);   // o = 4g..4g+3 <= 15 < 18
  const float bl16 = bl[16], bl17 = bl[17];
  const int rowc = (li < 2) ? (16 + li) : li;    // o-tile-1 A2 row (dummy rows harmless)

  const int sr = tid >> 4;   // staging row 0..31
  const int g4 = tid & 15;   // staging 4-float granule 0..15
  const int cbase = blockIdx.x * NCH;

  // stage-write: f32x4 -> fp16 (RNE), 8B write, 16B-chunk XOR swizzle
  // (chunk c16 = (g4>>1)^(sr&7)). Verbatim R14.
  auto stage_write = [&](int p, f32x4 v) {
    union { _Float16 h[4]; u32x2 u; } cv;
    cv.h[0] = (_Float16)v.x; cv.h[1] = (_Float16)v.y;
    cv.h[2] = (_Float16)v.z; cv.h[3] = (_Float16)v.w;
    const int offs = sr*DIM + 8*((g4 >> 1) ^ (sr & 7)) + 4*(g4 & 1);
    *(u32x2*)(&xh16[p][offs]) = cv.u;
  };

  // prologue: stage chunk 0 into buf 0 (also covers wlds/a1 init sync)
  {
    const float* xp = x + ((size_t)cbase * BM + sr) * DIM + 4*g4;
    stage_write(0, *(const f32x4*)xp);
  }
  asm volatile("s_waitcnt lgkmcnt(0)" ::: "memory");
  __builtin_amdgcn_s_barrier();
  asm volatile("" ::: "memory");

  for (int i = 0; i < NCH; ++i) {
    const int pb = i & 1;
    const int R  = (cbase + i) * BM;

    // ---- S1a: issue next chunk's x loads early (latency hides under P1) ----
    f32x4 pnext;
    const bool havenext = (i + 1 < NCH);
    if (havenext) {
      const float* xp = x + ((size_t)(R + BM) + sr) * DIM + 4*g4;
      pnext = *(const f32x4*)xp;
    }

    // ---- S1b: P1 on xh16[pb] -> featb[pb]. Single fp16 pass. Verbatim R14. ----
#pragma unroll
    for (int rt = 0; rt < 2; ++rt) {
      const int rr = rt*16 + li;
      const int m  = li & 7;                   // == rr&7
      f16x8 bh[2];
#pragma unroll
      for (int kb = 0; kb < 2; ++kb) {
        const int slot = 8*((4*kb + g) ^ m);
        bh[kb] = *(const f16x8*)(&xh16[pb][rr*DIM + slot]);
      }
      f32x4 acc[2];
#pragma unroll
      for (int q = 0; q < 2; ++q) acc[q] = f32x4{0.f, 0.f, 0.f, 0.f};
#pragma unroll
      for (int kb = 0; kb < 2; ++kb) {
#pragma unroll
        for (int q = 0; q < 2; ++q)
          acc[q] = __builtin_amdgcn_mfma_f32_16x16x32_f16(a1[q][kb], bh[kb], acc[q], 0, 0, 0);
      }
      // rev = proj + b_rbf; feat = cos(2*pi*rev)*SC, bf16, packed 8B write.
#pragma unroll
      for (int q = 0; q < 2; ++q) {
        float c4[4];
#pragma unroll
        for (int j = 0; j < 4; ++j) {
          float rev = acc[q][j] + brf[q][j];
          float f   = rev - floorf(rev);                 // [0,1) revolutions
          c4[j] = __builtin_amdgcn_cosf(f) * SC;
        }
        u32x2 pk;
        pk.x = cvt_pk_bf16(c4[0], c4[1]);
        pk.y = cvt_pk_bf16(c4[2], c4[3]);
        const int nt   = 2*wav + q;
        const int slot = (2*nt + (g >> 1)) ^ m;          // 16B-chunk XOR swizzle
        *(u32x2*)(&featb[pb][rr*256 + slot*8 + (g & 1)*4]) = pk;
      }
    }

    // ---- S1c: write next chunk's xh16 (other parity) ----
    if (havenext) stage_write(pb ^ 1, pnext);

    // ---- single barrier per chunk ----
    asm volatile("s_waitcnt lgkmcnt(0)" ::: "memory");
    __builtin_amdgcn_s_barrier();
    asm volatile("" ::: "memory");

    // ---- S2: P2 on featb[pb], spread over 4 waves: wave = (ot, rt2).
    // Verbatim R14 body. ----
    if (wav < 4) {
      const int rt2 = wav & 1;
      const int ot  = wav >> 1;
      const int rr  = rt2*16 + li;              // rows 0..31
      const int m   = li & 7;                   // == rr&7
      const int arow = (ot == 0) ? li : rowc;
      const int asw  = arow & 7;
      f32x4 acc2 = f32x4{0.f,0.f,0.f,0.f};
#pragma unroll
      for (int kb = 0; kb < 8; ++kb) {
        bf16x8 b2  = *(const bf16x8*)(&featb[pb][rr*256 + (((4*kb + g) ^ m) * 8)]);
        bf16x8 a2f = *(const bf16x8*)(&wlds[arow*NC + 8*((4*kb + g) ^ asw)]);
        acc2 = __builtin_amdgcn_mfma_f32_16x16x32_bf16(a2f, b2, acc2, 0, 0, 0);
      }
      float* op = out + (size_t)(R + rr) * OUTD;
      if (ot == 0) {
        f32x2 s0; s0.x = acc2.x + bl0.x; s0.y = acc2.y + bl0.y;
        f32x2 s1; s1.x = acc2.z + bl0.z; s1.y = acc2.w + bl0.w;
        *(f32x2*)(op + 4*g)     = s0;   // o = 4g..4g+3 (all < 16)
        *(f32x2*)(op + 4*g + 2) = s1;
      } else if (g == 0) {              // o = 16,17
        f32x2 s2; s2.x = acc2.x + bl16; s2.y = acc2.y + bl17;
        *(f32x2*)(op + 16) = s2;
      }
    }
  }
}

extern "C" void kernel_launch(void* const* d_in, const int* in_sizes, int n_in,
                              void* d_out, int out_size, void* d_ws, size_t ws_size,
                              hipStream_t stream) {
  (void)in_sizes; (void)n_in; (void)d_ws; (void)ws_size; (void)out_size;
  const float* x  = (const float*)d_in[0];
  const float* Wr = (const float*)d_in[1];
  const float* br = (const float*)d_in[2];
  const float* Wl = (const float*)d_in[3];
  const float* bl = (const float*)d_in[4];
  rbf_fused<<<NBLK, 512, 0, stream>>>(x, Wr, br, Wl, bl, (float*)d_out);
}

// Round 20
// 31.338 us; speedup vs baseline: 1.1265x; 1.0181x over previous
//
#include <hip/hip_runtime.h>
#include <cstdint>
#include <cstddef>

typedef __attribute__((ext_vector_type(8))) short bf16x8;
typedef __attribute__((ext_vector_type(8))) _Float16 f16x8;
typedef __attribute__((ext_vector_type(4))) float f32x4;
typedef __attribute__((ext_vector_type(2))) float f32x2;
typedef __attribute__((ext_vector_type(2))) unsigned int u32x2;

static constexpr int BROWS  = 262144;
static constexpr int DIM    = 64;
static constexpr int NC     = 256;
static constexpr int OUTD   = 18;
static constexpr int BM     = 32;              // rows per chunk
static constexpr int NCHTOT = BROWS / BM;      // 8192 chunks
static constexpr int NBLK   = 768;             // exactly 3 blocks/CU x 256 CUs

__device__ __forceinline__ unsigned cvt_pk_bf16(float a, float b) {
  unsigned r;
  asm("v_cvt_pk_bf16_f32 %0, %1, %2" : "=v"(r) : "v"(a), "v"(b));
  return r;
}

union U4 { unsigned u[4]; bf16x8 v; };

// pack 8 f32 -> 8 bf16 (RN), order-preserving
__device__ __forceinline__ bf16x8 pack8(const float* s) {
  U4 r;
#pragma unroll
  for (int p = 0; p < 4; ++p) r.u[p] = cvt_pk_bf16(s[2*p], s[2*p+1]);
  return r.v;
}

// NOTE (gfx950): __launch_bounds__(512, 8) forces a 32-VGPR cap -> scratch
// spill (R9). (512,4) observed safe (R10-R19: VGPR 44-64, no spill).
// NOTE: the epilogue-rewrite family {C-init=brf, SC-fold into wlds, v_fract
// asm, cvt_pkrtz} produced 0.15-0.2-class failures in three independent
// skeletons (R5/R7/R17) with no identifiable mechanism — BANNED. This file
// keeps R14's plain epilogue verbatim.
__global__ __launch_bounds__(512, 4) void rbf_fused(
    const float* __restrict__ x,  const float* __restrict__ Wr,
    const float* __restrict__ br, const float* __restrict__ Wl,
    const float* __restrict__ bl, float* __restrict__ out)
{
  // R14/R19 skeleton: xh16 + featb double-buffered, ONE barrier per chunk.
  // 49 KB LDS -> 3 blocks/CU resident with NBLK=768 (grid-stride chunks).
  __shared__ __align__(16) unsigned short xh16[2][BM * DIM];    // x as fp16 bits, 2 x 4 KB
  __shared__ __align__(16) unsigned short featb[2][BM * NC];    // feat bf16 bits, 2 x 16 KB
  __shared__ __align__(16) unsigned short wlds[OUTD * NC];      // W_lin bf16 (raw), 9 KB

  const int tid  = threadIdx.x;
  const int wav  = tid >> 6;      // 0..7
  const int lane = tid & 63;
  const int li   = lane & 15;
  const int g    = lane >> 4;

  const float S1 = 0.22507907903927651f;  // sqrt(2)/(2*pi): proj in revolutions
  const float SC = 0.08838834764831845f;  // sqrt(2/256), applied to feat (R14 semantics)

  // ---- stage W_lin -> LDS (bf16, swizzled). Verbatim R14. ----
  for (int idx = tid; idx < OUTD * 32; idx += 512) {
    const int r = idx >> 5, c = idx & 31;
    f32x4 v0 = *(const f32x4*)(Wl + r*NC + 8*c);
    f32x4 v1 = *(const f32x4*)(Wl + r*NC + 8*c + 4);
    float v[8];
    v[0]=v0.x; v[1]=v0.y; v[2]=v0.z; v[3]=v0.w;
    v[4]=v1.x; v[5]=v1.y; v[6]=v1.z; v[7]=v1.w;
    *(bf16x8*)(&wlds[r*NC + 8*(c ^ (r & 7))]) = pack8(v);
  }

  // ---- hoist A1 = (S1 * W_rbf)^T tile fragments, single fp16.  nt = 2*wav + q ----
  f16x8 a1[2][2];
#pragma unroll
  for (int q = 0; q < 2; ++q) {
    const int n = 16 * (2*wav + q) + li;      // component index
#pragma unroll
    for (int kb = 0; kb < 2; ++kb) {
      f16x8 f;
#pragma unroll
      for (int j = 0; j < 8; ++j)
        f[j] = (_Float16)(Wr[(size_t)(32*kb + 8*g + j) * NC + n] * S1);
      a1[q][kb] = f;
    }
  }
  f32x4 brf[2];
#pragma unroll
  for (int q = 0; q < 2; ++q)
    brf[q] = *(const f32x4*)(br + 16*(2*wav + q) + 4*g);

  const f32x4 bl0 = *(const f32x4*)(bl + 4*g);   // o = 4g..4g+3 <= 15 < 18
  const float bl16 = bl[16], bl17 = bl[17];
  const int rowc = (li < 2) ? (16 + li) : li;    // o-tile-1 A2 row (dummy rows harmless)

  const int sr = tid >> 4;   // staging row 0..31
  const int g4 = tid & 15;   // staging 4-float granule 0..15

  // stage-write: f32x4 -> fp16 (RNE), 8B write, 16B-chunk XOR swizzle
  // (chunk c16 = (g4>>1)^(sr&7)). Verbatim R14.
  auto stage_write = [&](int p, f32x4 v) {
    union { _Float16 h[4]; u32x2 u; } cv;
    cv.h[0] = (_Float16)v.x; cv.h[1] = (_Float16)v.y;
    cv.h[2] = (_Float16)v.z; cv.h[3] = (_Float16)v.w;
    const int offs = sr*DIM + 8*((g4 >> 1) ^ (sr & 7)) + 4*(g4 & 1);
    *(u32x2*)(&xh16[p][offs]) = cv.u;
  };

  // prologue: stage this block's first chunk into buf 0
  {
    const float* xp = x + ((size_t)blockIdx.x * BM + sr) * DIM + 4*g4;
    stage_write(0, *(const f32x4*)xp);
  }
  asm volatile("s_waitcnt lgkmcnt(0)" ::: "memory");
  __builtin_amdgcn_s_barrier();
  asm volatile("" ::: "memory");

  // grid-stride over chunks: block b handles chunks b, b+768, b+1536, ...
  int pb = 0;
  for (int c = blockIdx.x; c < NCHTOT; c += NBLK, pb ^= 1) {
    const int R = c * BM;

    // ---- S1a: issue next chunk's x loads early (latency hides under P1) ----
    f32x4 pnext;
    const bool havenext = (c + NBLK < NCHTOT);
    if (havenext) {
      const float* xp = x + ((size_t)(c + NBLK) * BM + sr) * DIM + 4*g4;
      pnext = *(const f32x4*)xp;
    }

    // ---- S1b: P1 on xh16[pb] -> featb[pb]. Single fp16 pass. Verbatim R14. ----
#pragma unroll
    for (int rt = 0; rt < 2; ++rt) {
      const int rr = rt*16 + li;
      const int m  = li & 7;                   // == rr&7
      f16x8 bh[2];
#pragma unroll
      for (int kb = 0; kb < 2; ++kb) {
        const int slot = 8*((4*kb + g) ^ m);
        bh[kb] = *(const f16x8*)(&xh16[pb][rr*DIM + slot]);
      }
      f32x4 acc[2];
#pragma unroll
      for (int q = 0; q < 2; ++q) acc[q] = f32x4{0.f, 0.f, 0.f, 0.f};
#pragma unroll
      for (int kb = 0; kb < 2; ++kb) {
#pragma unroll
        for (int q = 0; q < 2; ++q)
          acc[q] = __builtin_amdgcn_mfma_f32_16x16x32_f16(a1[q][kb], bh[kb], acc[q], 0, 0, 0);
      }
      // rev = proj + b_rbf; feat = cos(2*pi*rev)*SC, bf16, packed 8B write.
#pragma unroll
      for (int q = 0; q < 2; ++q) {
        float c4[4];
#pragma unroll
        for (int j = 0; j < 4; ++j) {
          float rev = acc[q][j] + brf[q][j];
          float f   = rev - floorf(rev);                 // [0,1) revolutions
          c4[j] = __builtin_amdgcn_cosf(f) * SC;
        }
        u32x2 pk;
        pk.x = cvt_pk_bf16(c4[0], c4[1]);
        pk.y = cvt_pk_bf16(c4[2], c4[3]);
        const int nt   = 2*wav + q;
        const int slot = (2*nt + (g >> 1)) ^ m;          // 16B-chunk XOR swizzle
        *(u32x2*)(&featb[pb][rr*256 + slot*8 + (g & 1)*4]) = pk;
      }
    }

    // ---- S1c: write next chunk's xh16 (other parity) ----
    if (havenext) stage_write(pb ^ 1, pnext);

    // ---- single barrier per chunk ----
    asm volatile("s_waitcnt lgkmcnt(0)" ::: "memory");
    __builtin_amdgcn_s_barrier();
    asm volatile("" ::: "memory");

    // ---- S2: P2 on featb[pb], spread over 4 waves: wave = (ot, rt2).
    // Verbatim R14 body. ----
    if (wav < 4) {
      const int rt2 = wav & 1;
      const int ot  = wav >> 1;
      const int rr  = rt2*16 + li;              // rows 0..31
      const int m   = li & 7;                   // == rr&7
      const int arow = (ot == 0) ? li : rowc;
      const int asw  = arow & 7;
      f32x4 acc2 = f32x4{0.f,0.f,0.f,0.f};
#pragma unroll
      for (int kb = 0; kb < 8; ++kb) {
        bf16x8 b2  = *(const bf16x8*)(&featb[pb][rr*256 + (((4*kb + g) ^ m) * 8)]);
        bf16x8 a2f = *(const bf16x8*)(&wlds[arow*NC + 8*((4*kb + g) ^ asw)]);
        acc2 = __builtin_amdgcn_mfma_f32_16x16x32_bf16(a2f, b2, acc2, 0, 0, 0);
      }
      float* op = out + (size_t)(R + rr) * OUTD;
      if (ot == 0) {
        f32x2 s0; s0.x = acc2.x + bl0.x; s0.y = acc2.y + bl0.y;
        f32x2 s1; s1.x = acc2.z + bl0.z; s1.y = acc2.w + bl0.w;
        *(f32x2*)(op + 4*g)     = s0;   // o = 4g..4g+3 (all < 16)
        *(f32x2*)(op + 4*g + 2) = s1;
      } else if (g == 0) {              // o = 16,17
        f32x2 s2; s2.x = acc2.x + bl16; s2.y = acc2.y + bl17;
        *(f32x2*)(op + 16) = s2;
      }
    }
  }
}

extern "C" void kernel_launch(void* const* d_in, const int* in_sizes, int n_in,
                              void* d_out, int out_size, void* d_ws, size_t ws_size,
                              hipStream_t stream) {
  (void)in_sizes; (void)n_in; (void)d_ws; (void)ws_size; (void)out_size;
  const float* x  = (const float*)d_in[0];
  const float* Wr = (const float*)d_in[1];
  const float* br = (const float*)d_in[2];
  const float* Wl = (const float*)d_in[3];
  const float* bl = (const float*)d_in[4];
  rbf_fused<<<NBLK, 512, 0, stream>>>(x, Wr, br, Wl, bl, (float*)d_out);
}